// Round 1
// baseline (692.189 us; speedup 1.0000x reference)
//
#include <hip/hip_runtime.h>
#include <cstdint>
#include <cstddef>

static inline int cdiv(int a, int b){ return (a + b - 1) / b; }

// ---------------- CSR build ----------------

__global__ __launch_bounds__(256) void count_kernel(const int* __restrict__ dst, int* __restrict__ counts, int E){
  int i = blockIdx.x * 256 + threadIdx.x;
  if (i < E) atomicAdd(&counts[dst[i]], 1);
}

__global__ __launch_bounds__(256) void dinv_kernel(const int* __restrict__ counts, float* __restrict__ dinv, int n){
  int i = blockIdx.x * 256 + threadIdx.x;
  if (i < n) dinv[i] = rsqrtf((float)counts[i] + 1.0f);
}

__global__ __launch_bounds__(256) void partial_kernel(const int* __restrict__ counts, int* __restrict__ bsum, int n){
  __shared__ int sdata[256];
  int b = blockIdx.x, t = threadIdx.x;
  int base = b * 1024 + t * 4;
  int s = 0;
  #pragma unroll
  for (int i = 0; i < 4; i++) if (base + i < n) s += counts[base + i];
  sdata[t] = s; __syncthreads();
  for (int off = 128; off > 0; off >>= 1){
    if (t < off) sdata[t] += sdata[t + off];
    __syncthreads();
  }
  if (t == 0) bsum[b] = sdata[0];
}

__global__ void scan_partials_kernel(const int* __restrict__ bsum, int* __restrict__ bsum_ex,
                                     int* __restrict__ row_off, int nblocks, int n){
  int run = 0;
  for (int i = 0; i < nblocks; i++){ bsum_ex[i] = run; run += bsum[i]; }
  row_off[n] = run;
}

__global__ __launch_bounds__(256) void scan_chunk_kernel(const int* __restrict__ counts, const int* __restrict__ bsum_ex,
                                                         int* __restrict__ row_off, int n){
  __shared__ int sdata[256];
  int b = blockIdx.x, t = threadIdx.x;
  int base = b * 1024 + t * 4;
  int c0 = (base + 0 < n) ? counts[base + 0] : 0;
  int c1 = (base + 1 < n) ? counts[base + 1] : 0;
  int c2 = (base + 2 < n) ? counts[base + 2] : 0;
  int c3 = (base + 3 < n) ? counts[base + 3] : 0;
  int tsum = c0 + c1 + c2 + c3;
  sdata[t] = tsum; __syncthreads();
  for (int off = 1; off < 256; off <<= 1){
    int v = (t >= off) ? sdata[t - off] : 0;
    __syncthreads();
    sdata[t] += v;
    __syncthreads();
  }
  int run = bsum_ex[b] + sdata[t] - tsum;
  if (base + 0 < n){ row_off[base + 0] = run; run += c0; }
  if (base + 1 < n){ row_off[base + 1] = run; run += c1; }
  if (base + 2 < n){ row_off[base + 2] = run; run += c2; }
  if (base + 3 < n){ row_off[base + 3] = run; run += c3; }
}

__global__ __launch_bounds__(256) void csr_fill_kernel(const int* __restrict__ src, const int* __restrict__ dst,
                                                       const int* __restrict__ row_off, int* __restrict__ cursor,
                                                       int* __restrict__ csr_src, int E){
  int i = blockIdx.x * 256 + threadIdx.x;
  if (i < E){
    int d = dst[i];
    int p = row_off[d] + atomicAdd(&cursor[d], 1);
    csr_src[p] = src[i];
  }
}

// ---------------- fp32 GEMM: C[M x BN] = A[M x K] @ B[K x BN] ----------------
// BM=128, BK=16, 256 threads, 8x8 register tile per thread (split 4+4 across 64-row/64-col halves).

template<int BN>
__global__ __launch_bounds__(256) void gemm_kernel(const float* __restrict__ A, const float* __restrict__ B,
                                                   float* __restrict__ C, int M, int K){
  constexpr int BM = 128, BK = 16;
  constexpr int G = BN / 64;         // column groups (2 for BN=128, 1 for BN=64)
  __shared__ float As[BK][BM + 4];   // +4 keeps 16B alignment, breaks power-of-2 stride
  __shared__ float Bs[BK][BN];
  int t = threadIdx.x;
  int tx = t & 15, ty = t >> 4;
  int m0 = blockIdx.x * BM;
  float acc[8][4 * G];
  #pragma unroll
  for (int r = 0; r < 8; r++)
    #pragma unroll
    for (int c = 0; c < 4 * G; c++) acc[r][c] = 0.f;

  for (int k0 = 0; k0 < K; k0 += BK){
    // A tile 128x16 -> As[k][m] (transposed), 2 float4 per thread
    #pragma unroll
    for (int i = 0; i < 2; i++){
      int idx = t + i * 256;
      int row = idx >> 2;
      int c4  = idx & 3;
      int grow = m0 + row;
      float4 v = make_float4(0.f, 0.f, 0.f, 0.f);
      if (grow < M) v = *reinterpret_cast<const float4*>(A + (size_t)grow * K + k0 + c4 * 4);
      As[c4 * 4 + 0][row] = v.x;
      As[c4 * 4 + 1][row] = v.y;
      As[c4 * 4 + 2][row] = v.z;
      As[c4 * 4 + 3][row] = v.w;
    }
    // B tile 16xBN, row-major copy
    #pragma unroll
    for (int i = 0; i < G; i++){
      int idx = t + i * 256;
      int row = idx / (BN / 4);
      int c4  = idx % (BN / 4);
      *reinterpret_cast<float4*>(&Bs[row][c4 * 4]) =
        *reinterpret_cast<const float4*>(B + (size_t)(k0 + row) * BN + c4 * 4);
    }
    __syncthreads();
    #pragma unroll
    for (int k = 0; k < BK; k++){
      float a[8], bb[4 * G];
      *reinterpret_cast<float4*>(&a[0]) = *reinterpret_cast<const float4*>(&As[k][ty * 4]);
      *reinterpret_cast<float4*>(&a[4]) = *reinterpret_cast<const float4*>(&As[k][64 + ty * 4]);
      *reinterpret_cast<float4*>(&bb[0]) = *reinterpret_cast<const float4*>(&Bs[k][tx * 4]);
      if (G == 2)
        *reinterpret_cast<float4*>(&bb[4]) = *reinterpret_cast<const float4*>(&Bs[k][64 + tx * 4]);
      #pragma unroll
      for (int r = 0; r < 8; r++)
        #pragma unroll
        for (int c = 0; c < 4 * G; c++)
          acc[r][c] = fmaf(a[r], bb[c], acc[r][c]);
    }
    __syncthreads();
  }
  #pragma unroll
  for (int r = 0; r < 8; r++){
    int lr = (r < 4) ? (ty * 4 + r) : (64 + ty * 4 + (r - 4));
    int row = m0 + lr;
    if (row < M){
      float4 v0 = make_float4(acc[r][0], acc[r][1], acc[r][2], acc[r][3]);
      *reinterpret_cast<float4*>(C + (size_t)row * BN + tx * 4) = v0;
      if (G == 2){
        float4 v1 = make_float4(acc[r][4], acc[r][5], acc[r][6], acc[r][7]);
        *reinterpret_cast<float4*>(C + (size_t)row * BN + 64 + tx * 4) = v1;
      }
    }
  }
}

// ---------------- aggregation: out = relu(dinv_i*(sum dinv_s h_s) + dinv_i^2 h_i + b) ----------------
// one wave per node; DH=128: lane owns cols {2*lane, 2*lane+1}

__global__ __launch_bounds__(256) void agg128_kernel(const float* __restrict__ h, const int* __restrict__ row_off,
                                                     const int* __restrict__ csr_src, const float* __restrict__ dinv,
                                                     const float* __restrict__ bias, float* __restrict__ out, int n){
  int node = blockIdx.x * 4 + (threadIdx.x >> 6);
  if (node >= n) return;
  int lane = threadIdx.x & 63;
  int e = row_off[node], eend = row_off[node + 1];
  float di = dinv[node];
  float ax = 0.f, ay = 0.f;
  for (; e + 4 <= eend; e += 4){
    int s0 = csr_src[e], s1 = csr_src[e + 1], s2 = csr_src[e + 2], s3 = csr_src[e + 3];
    float w0 = dinv[s0], w1 = dinv[s1], w2 = dinv[s2], w3 = dinv[s3];
    float2 v0 = *reinterpret_cast<const float2*>(h + (size_t)s0 * 128 + lane * 2);
    float2 v1 = *reinterpret_cast<const float2*>(h + (size_t)s1 * 128 + lane * 2);
    float2 v2 = *reinterpret_cast<const float2*>(h + (size_t)s2 * 128 + lane * 2);
    float2 v3 = *reinterpret_cast<const float2*>(h + (size_t)s3 * 128 + lane * 2);
    ax += w0 * v0.x + w1 * v1.x + w2 * v2.x + w3 * v3.x;
    ay += w0 * v0.y + w1 * v1.y + w2 * v2.y + w3 * v3.y;
  }
  for (; e < eend; ++e){
    int s = csr_src[e];
    float w = dinv[s];
    float2 v = *reinterpret_cast<const float2*>(h + (size_t)s * 128 + lane * 2);
    ax += w * v.x; ay += w * v.y;
  }
  float2 hv = *reinterpret_cast<const float2*>(h + (size_t)node * 128 + lane * 2);
  float2 bv = *reinterpret_cast<const float2*>(bias + lane * 2);
  float ox = fmaxf(fmaf(di, ax, di * di * hv.x) + bv.x, 0.f);
  float oy = fmaxf(fmaf(di, ay, di * di * hv.y) + bv.y, 0.f);
  float2 o = make_float2(ox, oy);
  *reinterpret_cast<float2*>(out + (size_t)node * 128 + lane * 2) = o;
}

__global__ __launch_bounds__(256) void agg64_kernel(const float* __restrict__ h, const int* __restrict__ row_off,
                                                    const int* __restrict__ csr_src, const float* __restrict__ dinv,
                                                    const float* __restrict__ bias, float* __restrict__ out, int n){
  int node = blockIdx.x * 4 + (threadIdx.x >> 6);
  if (node >= n) return;
  int lane = threadIdx.x & 63;
  int e = row_off[node], eend = row_off[node + 1];
  float di = dinv[node];
  float ax = 0.f;
  for (; e + 4 <= eend; e += 4){
    int s0 = csr_src[e], s1 = csr_src[e + 1], s2 = csr_src[e + 2], s3 = csr_src[e + 3];
    float w0 = dinv[s0], w1 = dinv[s1], w2 = dinv[s2], w3 = dinv[s3];
    float v0 = h[(size_t)s0 * 64 + lane];
    float v1 = h[(size_t)s1 * 64 + lane];
    float v2 = h[(size_t)s2 * 64 + lane];
    float v3 = h[(size_t)s3 * 64 + lane];
    ax += w0 * v0 + w1 * v1 + w2 * v2 + w3 * v3;
  }
  for (; e < eend; ++e){
    int s = csr_src[e];
    ax += dinv[s] * h[(size_t)s * 64 + lane];
  }
  float hv = h[(size_t)node * 64 + lane];
  float o = fmaxf(fmaf(di, ax, di * di * hv) + bias[lane], 0.f);
  out[(size_t)node * 64 + lane] = o;
}

// ---------------- classifier: out[i] = dot(g[i], Wc) + bc ----------------

__global__ __launch_bounds__(256) void cls_kernel(const float* __restrict__ g, const float* __restrict__ Wc,
                                                  const float* __restrict__ bc, float* __restrict__ out, int n){
  int node = blockIdx.x * 4 + (threadIdx.x >> 6);
  if (node >= n) return;
  int lane = threadIdx.x & 63;
  float v = g[(size_t)node * 64 + lane] * Wc[lane];
  #pragma unroll
  for (int off = 32; off > 0; off >>= 1) v += __shfl_down(v, off);
  if (lane == 0) out[node] = v + bc[0];
}

// ---------------- launch ----------------

extern "C" void kernel_launch(void* const* d_in, const int* in_sizes, int n_in,
                              void* d_out, int out_size, void* d_ws, size_t ws_size,
                              hipStream_t stream){
  const float* x  = (const float*)d_in[0];
  const int*   ei = (const int*)d_in[1];
  const float* W1 = (const float*)d_in[2];
  const float* b1 = (const float*)d_in[3];
  const float* W2 = (const float*)d_in[4];
  const float* b2 = (const float*)d_in[5];
  const float* W3 = (const float*)d_in[6];
  const float* b3 = (const float*)d_in[7];
  const float* Wc = (const float*)d_in[8];
  const float* bc = (const float*)d_in[9];
  float* out = (float*)d_out;

  int N = in_sizes[0] / 256;
  int E = in_sizes[1] / 2;
  const int* src = ei;
  const int* dst = ei + E;

  char* ws = (char*)d_ws;
  size_t off = 0;
  auto alloc = [&](size_t bytes) -> char* {
    char* p = ws + off;
    off += (bytes + 511) & ~(size_t)511;
    return p;
  };
  int*   counts  = (int*)  alloc((size_t)N * 4);       // reused as cursor after scan
  float* dinv    = (float*)alloc((size_t)N * 4);
  int*   row_off = (int*)  alloc(((size_t)N + 1) * 4);
  int*   bsum    = (int*)  alloc(1024);
  int*   bsum_ex = (int*)  alloc(1024);
  int*   csr_src = (int*)  alloc((size_t)E * 4);
  float* bufA    = (float*)alloc((size_t)N * 128 * 4);
  float* bufB    = (float*)alloc((size_t)N * 128 * 4);

  int NB = (N + 1023) / 1024;

  hipMemsetAsync(counts, 0, (size_t)N * 4, stream);
  count_kernel<<<cdiv(E, 256), 256, 0, stream>>>(dst, counts, E);
  dinv_kernel<<<cdiv(N, 256), 256, 0, stream>>>(counts, dinv, N);
  partial_kernel<<<NB, 256, 0, stream>>>(counts, bsum, N);
  scan_partials_kernel<<<1, 1, 0, stream>>>(bsum, bsum_ex, row_off, NB, N);
  scan_chunk_kernel<<<NB, 256, 0, stream>>>(counts, bsum_ex, row_off, N);
  hipMemsetAsync(counts, 0, (size_t)N * 4, stream);   // counts -> cursor
  csr_fill_kernel<<<cdiv(E, 256), 256, 0, stream>>>(src, dst, row_off, counts, csr_src, E);

  // layer 1: x[N,256] @ W1[256,128] -> bufA; agg -> bufB
  gemm_kernel<128><<<cdiv(N, 128), 256, 0, stream>>>(x, W1, bufA, N, 256);
  agg128_kernel<<<cdiv(N, 4), 256, 0, stream>>>(bufA, row_off, csr_src, dinv, b1, bufB, N);
  // layer 2
  gemm_kernel<128><<<cdiv(N, 128), 256, 0, stream>>>(bufB, W2, bufA, N, 128);
  agg128_kernel<<<cdiv(N, 4), 256, 0, stream>>>(bufA, row_off, csr_src, dinv, b2, bufB, N);
  // layer 3 (128 -> 64)
  gemm_kernel<64><<<cdiv(N, 128), 256, 0, stream>>>(bufB, W3, bufA, N, 128);
  agg64_kernel<<<cdiv(N, 4), 256, 0, stream>>>(bufA, row_off, csr_src, dinv, b3, bufB, N);
  // classifier
  cls_kernel<<<cdiv(N, 4), 256, 0, stream>>>(bufB, Wc, bc, out, N);
}

// Round 2
// 620.667 us; speedup vs baseline: 1.1152x; 1.1152x over previous
//
#include <hip/hip_runtime.h>
#include <hip/hip_fp16.h>
#include <cstdint>
#include <cstddef>

static inline int cdiv(int a, int b){ return (a + b - 1) / b; }

// ---------------- CSR build ----------------

__global__ __launch_bounds__(256) void count_kernel(const int* __restrict__ dst, int* __restrict__ counts, int E){
  int i = blockIdx.x * 256 + threadIdx.x;
  if (i < E) atomicAdd(&counts[dst[i]], 1);
}

__global__ __launch_bounds__(256) void dinv_kernel(const int* __restrict__ counts, float* __restrict__ dinv, int n){
  int i = blockIdx.x * 256 + threadIdx.x;
  if (i < n) dinv[i] = rsqrtf((float)counts[i] + 1.0f);
}

__global__ __launch_bounds__(256) void partial_kernel(const int* __restrict__ counts, int* __restrict__ bsum, int n){
  __shared__ int sdata[256];
  int b = blockIdx.x, t = threadIdx.x;
  int base = b * 1024 + t * 4;
  int s = 0;
  #pragma unroll
  for (int i = 0; i < 4; i++) if (base + i < n) s += counts[base + i];
  sdata[t] = s; __syncthreads();
  for (int off = 128; off > 0; off >>= 1){
    if (t < off) sdata[t] += sdata[t + off];
    __syncthreads();
  }
  if (t == 0) bsum[b] = sdata[0];
}

__global__ void scan_partials_kernel(const int* __restrict__ bsum, int* __restrict__ bsum_ex,
                                     int* __restrict__ row_off, int nblocks, int n){
  int run = 0;
  for (int i = 0; i < nblocks; i++){ bsum_ex[i] = run; run += bsum[i]; }
  row_off[n] = run;
}

__global__ __launch_bounds__(256) void scan_chunk_kernel(const int* __restrict__ counts, const int* __restrict__ bsum_ex,
                                                         int* __restrict__ row_off, int n){
  __shared__ int sdata[256];
  int b = blockIdx.x, t = threadIdx.x;
  int base = b * 1024 + t * 4;
  int c0 = (base + 0 < n) ? counts[base + 0] : 0;
  int c1 = (base + 1 < n) ? counts[base + 1] : 0;
  int c2 = (base + 2 < n) ? counts[base + 2] : 0;
  int c3 = (base + 3 < n) ? counts[base + 3] : 0;
  int tsum = c0 + c1 + c2 + c3;
  sdata[t] = tsum; __syncthreads();
  for (int off = 1; off < 256; off <<= 1){
    int v = (t >= off) ? sdata[t - off] : 0;
    __syncthreads();
    sdata[t] += v;
    __syncthreads();
  }
  int run = bsum_ex[b] + sdata[t] - tsum;
  if (base + 0 < n){ row_off[base + 0] = run; run += c0; }
  if (base + 1 < n){ row_off[base + 1] = run; run += c1; }
  if (base + 2 < n){ row_off[base + 2] = run; run += c2; }
  if (base + 3 < n){ row_off[base + 3] = run; run += c3; }
}

__global__ __launch_bounds__(256) void csr_fill_kernel(const int* __restrict__ src, const int* __restrict__ dst,
                                                       const int* __restrict__ row_off, int* __restrict__ cursor,
                                                       int* __restrict__ csr_src, int E){
  int i = blockIdx.x * 256 + threadIdx.x;
  if (i < E){
    int d = dst[i];
    int p = row_off[d] + atomicAdd(&cursor[d], 1);
    csr_src[p] = src[i];
  }
}

// ---------------- fp32 GEMM -> fp16 output: C16[M x BN] = half(A[M x K] @ B[K x BN]) ----------------
// BM=128, BK=32, 256 threads, 8x8 register tile per thread.

template<int BN>
__global__ __launch_bounds__(256) void gemm_kernel(const float* __restrict__ A, const float* __restrict__ B,
                                                   __half* __restrict__ C16, int M, int K){
  constexpr int BM = 128, BK = 32;
  constexpr int G = BN / 64;         // column groups (2 for BN=128, 1 for BN=64)
  __shared__ float As[BK][BM + 4];
  __shared__ float Bs[BK][BN];
  int t = threadIdx.x;
  int tx = t & 15, ty = t >> 4;
  int m0 = blockIdx.x * BM;
  float acc[8][4 * G];
  #pragma unroll
  for (int r = 0; r < 8; r++)
    #pragma unroll
    for (int c = 0; c < 4 * G; c++) acc[r][c] = 0.f;

  for (int k0 = 0; k0 < K; k0 += BK){
    // A tile 128x32 -> As[k][m] (transposed), 4 float4 per thread
    #pragma unroll
    for (int i = 0; i < 4; i++){
      int idx = t + i * 256;
      int row = idx >> 3;         // 8 float4 per 32-float row
      int c4  = idx & 7;
      int grow = m0 + row;
      float4 v = make_float4(0.f, 0.f, 0.f, 0.f);
      if (grow < M) v = *reinterpret_cast<const float4*>(A + (size_t)grow * K + k0 + c4 * 4);
      As[c4 * 4 + 0][row] = v.x;
      As[c4 * 4 + 1][row] = v.y;
      As[c4 * 4 + 2][row] = v.z;
      As[c4 * 4 + 3][row] = v.w;
    }
    // B tile 32xBN, row-major copy: BN/32 float4 per thread
    #pragma unroll
    for (int i = 0; i < BN / 32; i++){
      int idx = t + i * 256;
      int row = idx / (BN / 4);
      int c4  = idx % (BN / 4);
      *reinterpret_cast<float4*>(&Bs[row][c4 * 4]) =
        *reinterpret_cast<const float4*>(B + (size_t)(k0 + row) * BN + c4 * 4);
    }
    __syncthreads();
    #pragma unroll
    for (int k = 0; k < BK; k++){
      float a[8], bb[4 * G];
      *reinterpret_cast<float4*>(&a[0]) = *reinterpret_cast<const float4*>(&As[k][ty * 4]);
      *reinterpret_cast<float4*>(&a[4]) = *reinterpret_cast<const float4*>(&As[k][64 + ty * 4]);
      *reinterpret_cast<float4*>(&bb[0]) = *reinterpret_cast<const float4*>(&Bs[k][tx * 4]);
      if (G == 2)
        *reinterpret_cast<float4*>(&bb[4]) = *reinterpret_cast<const float4*>(&Bs[k][64 + tx * 4]);
      #pragma unroll
      for (int r = 0; r < 8; r++)
        #pragma unroll
        for (int c = 0; c < 4 * G; c++)
          acc[r][c] = fmaf(a[r], bb[c], acc[r][c]);
    }
    __syncthreads();
  }
  #pragma unroll
  for (int r = 0; r < 8; r++){
    int lr = (r < 4) ? (ty * 4 + r) : (64 + ty * 4 + (r - 4));
    int row = m0 + lr;
    if (row < M){
      __half t0[4];
      #pragma unroll
      for (int j = 0; j < 4; j++) t0[j] = __float2half(acc[r][j]);
      *reinterpret_cast<uint2*>(C16 + (size_t)row * BN + tx * 4) = *reinterpret_cast<uint2*>(t0);
      if (G == 2){
        __half t1[4];
        #pragma unroll
        for (int j = 0; j < 4; j++) t1[j] = __float2half(acc[r][4 + j]);
        *reinterpret_cast<uint2*>(C16 + (size_t)row * BN + 64 + tx * 4) = *reinterpret_cast<uint2*>(t1);
      }
    }
  }
}

// ---------------- aggregation (fp16 gather): out = relu(di*(sum dinv_s h_s) + di^2 h_i + b) ----------------
// one wave per node; DH=128: lane owns cols {2*lane, 2*lane+1} as __half2

__global__ __launch_bounds__(256) void agg128h_kernel(const __half* __restrict__ h16, const int* __restrict__ row_off,
                                                      const int* __restrict__ csr_src, const float* __restrict__ dinv,
                                                      const float* __restrict__ bias, float* __restrict__ out, int n){
  int node = blockIdx.x * 4 + (threadIdx.x >> 6);
  if (node >= n) return;
  int lane = threadIdx.x & 63;
  int e = row_off[node], eend = row_off[node + 1];
  float di = dinv[node];
  float ax = 0.f, ay = 0.f;
  for (; e + 8 <= eend; e += 8){
    int s[8]; float w[8]; __half2 v[8];
    #pragma unroll
    for (int i = 0; i < 8; i++) s[i] = csr_src[e + i];
    #pragma unroll
    for (int i = 0; i < 8; i++) w[i] = dinv[s[i]];
    #pragma unroll
    for (int i = 0; i < 8; i++)
      v[i] = *reinterpret_cast<const __half2*>(h16 + (size_t)s[i] * 128 + lane * 2);
    #pragma unroll
    for (int i = 0; i < 8; i++){
      float2 f = __half22float2(v[i]);
      ax = fmaf(w[i], f.x, ax);
      ay = fmaf(w[i], f.y, ay);
    }
  }
  for (; e < eend; ++e){
    int s = csr_src[e];
    float w = dinv[s];
    float2 f = __half22float2(*reinterpret_cast<const __half2*>(h16 + (size_t)s * 128 + lane * 2));
    ax = fmaf(w, f.x, ax);
    ay = fmaf(w, f.y, ay);
  }
  float2 hv = __half22float2(*reinterpret_cast<const __half2*>(h16 + (size_t)node * 128 + lane * 2));
  float2 bv = *reinterpret_cast<const float2*>(bias + lane * 2);
  float ox = fmaxf(fmaf(di, ax, di * di * hv.x) + bv.x, 0.f);
  float oy = fmaxf(fmaf(di, ay, di * di * hv.y) + bv.y, 0.f);
  *reinterpret_cast<float2*>(out + (size_t)node * 128 + lane * 2) = make_float2(ox, oy);
}

__global__ __launch_bounds__(256) void agg64h_kernel(const __half* __restrict__ h16, const int* __restrict__ row_off,
                                                     const int* __restrict__ csr_src, const float* __restrict__ dinv,
                                                     const float* __restrict__ bias, float* __restrict__ out, int n){
  int node = blockIdx.x * 4 + (threadIdx.x >> 6);
  if (node >= n) return;
  int lane = threadIdx.x & 63;
  int e = row_off[node], eend = row_off[node + 1];
  float di = dinv[node];
  float ax = 0.f;
  for (; e + 8 <= eend; e += 8){
    int s[8]; float w[8]; __half v[8];
    #pragma unroll
    for (int i = 0; i < 8; i++) s[i] = csr_src[e + i];
    #pragma unroll
    for (int i = 0; i < 8; i++) w[i] = dinv[s[i]];
    #pragma unroll
    for (int i = 0; i < 8; i++) v[i] = h16[(size_t)s[i] * 64 + lane];
    #pragma unroll
    for (int i = 0; i < 8; i++) ax = fmaf(w[i], __half2float(v[i]), ax);
  }
  for (; e < eend; ++e){
    int s = csr_src[e];
    ax = fmaf(dinv[s], __half2float(h16[(size_t)s * 64 + lane]), ax);
  }
  float hv = __half2float(h16[(size_t)node * 64 + lane]);
  float o = fmaxf(fmaf(di, ax, di * di * hv) + bias[lane], 0.f);
  out[(size_t)node * 64 + lane] = o;
}

// ---------------- classifier: out[i] = dot(g[i], Wc) + bc ----------------

__global__ __launch_bounds__(256) void cls_kernel(const float* __restrict__ g, const float* __restrict__ Wc,
                                                  const float* __restrict__ bc, float* __restrict__ out, int n){
  int node = blockIdx.x * 4 + (threadIdx.x >> 6);
  if (node >= n) return;
  int lane = threadIdx.x & 63;
  float v = g[(size_t)node * 64 + lane] * Wc[lane];
  #pragma unroll
  for (int off = 32; off > 0; off >>= 1) v += __shfl_down(v, off);
  if (lane == 0) out[node] = v + bc[0];
}

// ---------------- launch ----------------

extern "C" void kernel_launch(void* const* d_in, const int* in_sizes, int n_in,
                              void* d_out, int out_size, void* d_ws, size_t ws_size,
                              hipStream_t stream){
  const float* x  = (const float*)d_in[0];
  const int*   ei = (const int*)d_in[1];
  const float* W1 = (const float*)d_in[2];
  const float* b1 = (const float*)d_in[3];
  const float* W2 = (const float*)d_in[4];
  const float* b2 = (const float*)d_in[5];
  const float* W3 = (const float*)d_in[6];
  const float* b3 = (const float*)d_in[7];
  const float* Wc = (const float*)d_in[8];
  const float* bc = (const float*)d_in[9];
  float* out = (float*)d_out;

  int N = in_sizes[0] / 256;
  int E = in_sizes[1] / 2;
  const int* src = ei;
  const int* dst = ei + E;

  char* ws = (char*)d_ws;
  size_t off = 0;
  auto alloc = [&](size_t bytes) -> char* {
    char* p = ws + off;
    off += (bytes + 511) & ~(size_t)511;
    return p;
  };
  int*    counts  = (int*)   alloc((size_t)N * 4);     // reused as cursor after scan
  float*  dinv    = (float*) alloc((size_t)N * 4);
  int*    row_off = (int*)   alloc(((size_t)N + 1) * 4);
  int*    bsum    = (int*)   alloc(1024);
  int*    bsum_ex = (int*)   alloc(1024);
  int*    csr_src = (int*)   alloc((size_t)E * 4);
  float*  bufF    = (float*) alloc((size_t)N * 128 * 4);  // fp32 agg outputs
  __half* bufH    = (__half*)alloc((size_t)N * 128 * 2);  // fp16 gemm outputs

  int NB = (N + 1023) / 1024;

  hipMemsetAsync(counts, 0, (size_t)N * 4, stream);
  count_kernel<<<cdiv(E, 256), 256, 0, stream>>>(dst, counts, E);
  dinv_kernel<<<cdiv(N, 256), 256, 0, stream>>>(counts, dinv, N);
  partial_kernel<<<NB, 256, 0, stream>>>(counts, bsum, N);
  scan_partials_kernel<<<1, 1, 0, stream>>>(bsum, bsum_ex, row_off, NB, N);
  scan_chunk_kernel<<<NB, 256, 0, stream>>>(counts, bsum_ex, row_off, N);
  hipMemsetAsync(counts, 0, (size_t)N * 4, stream);   // counts -> cursor
  csr_fill_kernel<<<cdiv(E, 256), 256, 0, stream>>>(src, dst, row_off, counts, csr_src, E);

  // layer 1: x[N,256] @ W1[256,128] -> bufH (fp16); agg -> bufF (fp32)
  gemm_kernel<128><<<cdiv(N, 128), 256, 0, stream>>>(x, W1, bufH, N, 256);
  agg128h_kernel<<<cdiv(N, 4), 256, 0, stream>>>(bufH, row_off, csr_src, dinv, b1, bufF, N);
  // layer 2
  gemm_kernel<128><<<cdiv(N, 128), 256, 0, stream>>>(bufF, W2, bufH, N, 128);
  agg128h_kernel<<<cdiv(N, 4), 256, 0, stream>>>(bufH, row_off, csr_src, dinv, b2, bufF, N);
  // layer 3 (128 -> 64)
  gemm_kernel<64><<<cdiv(N, 128), 256, 0, stream>>>(bufF, W3, bufH, N, 128);
  agg64h_kernel<<<cdiv(N, 4), 256, 0, stream>>>(bufH, row_off, csr_src, dinv, b3, bufF, N);
  // classifier
  cls_kernel<<<cdiv(N, 4), 256, 0, stream>>>(bufF, Wc, bc, out, N);
}

// Round 4
// 492.050 us; speedup vs baseline: 1.4067x; 1.2614x over previous
//
#include <hip/hip_runtime.h>
#include <cstdint>
#include <cstddef>

typedef __attribute__((ext_vector_type(4))) float f32x4;
typedef __attribute__((ext_vector_type(8))) _Float16 half8v;
typedef __attribute__((ext_vector_type(2))) _Float16 half2v;

static inline int cdiv(int a, int b){ return (a + b - 1) / b; }

// ---------------- CSR build ----------------

__global__ __launch_bounds__(256) void count_kernel(const int* __restrict__ dst, int* __restrict__ counts, int E){
  int i = blockIdx.x * 256 + threadIdx.x;
  if (i < E) atomicAdd(&counts[dst[i]], 1);
}

__global__ __launch_bounds__(256) void dinv_kernel(const int* __restrict__ counts, float* __restrict__ dinv, int n){
  int i = blockIdx.x * 256 + threadIdx.x;
  if (i < n) dinv[i] = rsqrtf((float)counts[i] + 1.0f);
}

__global__ __launch_bounds__(256) void partial_kernel(const int* __restrict__ counts, int* __restrict__ bsum, int n){
  __shared__ int sdata[256];
  int b = blockIdx.x, t = threadIdx.x;
  int base = b * 1024 + t * 4;
  int s = 0;
  #pragma unroll
  for (int i = 0; i < 4; i++) if (base + i < n) s += counts[base + i];
  sdata[t] = s; __syncthreads();
  for (int off = 128; off > 0; off >>= 1){
    if (t < off) sdata[t] += sdata[t + off];
    __syncthreads();
  }
  if (t == 0) bsum[b] = sdata[0];
}

__global__ void scan_partials_kernel(const int* __restrict__ bsum, int* __restrict__ bsum_ex,
                                     int* __restrict__ row_off, int nblocks, int n){
  int run = 0;
  for (int i = 0; i < nblocks; i++){ bsum_ex[i] = run; run += bsum[i]; }
  row_off[n] = run;
}

__global__ __launch_bounds__(256) void scan_chunk_kernel(const int* __restrict__ counts, const int* __restrict__ bsum_ex,
                                                         int* __restrict__ row_off, int n){
  __shared__ int sdata[256];
  int b = blockIdx.x, t = threadIdx.x;
  int base = b * 1024 + t * 4;
  int c0 = (base + 0 < n) ? counts[base + 0] : 0;
  int c1 = (base + 1 < n) ? counts[base + 1] : 0;
  int c2 = (base + 2 < n) ? counts[base + 2] : 0;
  int c3 = (base + 3 < n) ? counts[base + 3] : 0;
  int tsum = c0 + c1 + c2 + c3;
  sdata[t] = tsum; __syncthreads();
  for (int off = 1; off < 256; off <<= 1){
    int v = (t >= off) ? sdata[t - off] : 0;
    __syncthreads();
    sdata[t] += v;
    __syncthreads();
  }
  int run = bsum_ex[b] + sdata[t] - tsum;
  if (base + 0 < n){ row_off[base + 0] = run; run += c0; }
  if (base + 1 < n){ row_off[base + 1] = run; run += c1; }
  if (base + 2 < n){ row_off[base + 2] = run; run += c2; }
  if (base + 3 < n){ row_off[base + 3] = run; run += c3; }
}

__global__ __launch_bounds__(256) void csr_fill_kernel(const int* __restrict__ src, const int* __restrict__ dst,
                                                       const int* __restrict__ row_off, int* __restrict__ cursor,
                                                       int* __restrict__ csr_src, int E){
  int i = blockIdx.x * 256 + threadIdx.x;
  if (i < E){
    int d = dst[i];
    int p = row_off[d] + atomicAdd(&cursor[d], 1);
    csr_src[p] = src[i];
  }
}

// ---------------- weight convert + transpose: Wt[n][k] = fp16(W[k][n]) ----------------

__global__ __launch_bounds__(256) void wcvt_kernel(const float* __restrict__ W, _Float16* __restrict__ Wt, int K, int N){
  int i = blockIdx.x * 256 + threadIdx.x;
  if (i < K * N){
    int k = i / N, n = i - k * N;
    Wt[(size_t)n * K + k] = (_Float16)W[i];
  }
}

// ---------------- MFMA GEMM: C16[M x BN] = fp16(A[M x K] @ Bt^T), Bt is [BN x K] fp16 ----------------
// BM=128, BK=32, 4 waves. v_mfma_f32_16x16x32_f16 fragments (m92/m97 ladder layout):
//   A: lane l holds row (l&15), k = 8*(l>>4)+{0..7}  (contiguous half8 in a [row][k] LDS tile)
//   B: lane l holds col (l&15), same k               (contiguous half8 in a [col][k] tile = Bt layout)
//   D: lane l reg r -> row = 4*(l>>4)+r, col = (l&15)   [m89-verified, dtype-independent]

template<int BN, bool A32IN>
__global__ __launch_bounds__(256) void mgemm_kernel(const void* __restrict__ Ain, const _Float16* __restrict__ Bt,
                                                    _Float16* __restrict__ C16, int M, int K){
  constexpr int BM = 128, BK = 32, LD = 40;  // stride 40 halves: 16B-aligned rows, <=2-way bank aliasing
  constexpr int MF = (BN == 128) ? 4 : 2;
  __shared__ _Float16 As[BM * LD];
  __shared__ _Float16 Bs[BN * LD];
  const float*    A32 = (const float*)Ain;
  const _Float16* A16 = (const _Float16*)Ain;
  int t = threadIdx.x;
  int w = t >> 6, l = t & 63;
  int m0 = blockIdx.x * BM;
  int wm = (BN == 128) ? (w >> 1) * 64 : w * 32;
  int wn = (BN == 128) ? (w & 1) * 64 : 0;
  int lr = l & 15;
  int kg = (l >> 4) * 8;

  f32x4 acc[MF][4];
  #pragma unroll
  for (int i = 0; i < MF; i++)
    #pragma unroll
    for (int j = 0; j < 4; j++){
      f32x4 z = {0.f, 0.f, 0.f, 0.f};
      acc[i][j] = z;
    }

  for (int k0 = 0; k0 < K; k0 += BK){
    __syncthreads();   // protect LDS from previous iteration's readers
    // stage A tile: BM rows x 32 halves, 16B chunks
    #pragma unroll
    for (int j = 0; j < (BM * 4) / 256; j++){
      int i = t + j * 256;
      int row = i >> 2, c = i & 3;
      int gr = m0 + row;
      half8v hv = {(_Float16)0, (_Float16)0, (_Float16)0, (_Float16)0,
                   (_Float16)0, (_Float16)0, (_Float16)0, (_Float16)0};
      if (gr < M){
        if (A32IN){
          const float* ap = A32 + (size_t)gr * K + k0 + c * 8;
          float4 f0 = *reinterpret_cast<const float4*>(ap);
          float4 f1 = *reinterpret_cast<const float4*>(ap + 4);
          hv[0] = (_Float16)f0.x; hv[1] = (_Float16)f0.y; hv[2] = (_Float16)f0.z; hv[3] = (_Float16)f0.w;
          hv[4] = (_Float16)f1.x; hv[5] = (_Float16)f1.y; hv[6] = (_Float16)f1.z; hv[7] = (_Float16)f1.w;
        } else {
          hv = *reinterpret_cast<const half8v*>(A16 + (size_t)gr * K + k0 + c * 8);
        }
      }
      *reinterpret_cast<half8v*>(&As[row * LD + c * 8]) = hv;
    }
    // stage Bt tile: BN rows (cols of B) x 32 halves
    #pragma unroll
    for (int j = 0; j < (BN * 4) / 256; j++){
      int i = t + j * 256;
      int row = i >> 2, c = i & 3;
      *reinterpret_cast<half8v*>(&Bs[row * LD + c * 8]) =
        *reinterpret_cast<const half8v*>(Bt + (size_t)row * K + k0 + c * 8);
    }
    __syncthreads();
    half8v af[MF];
    #pragma unroll
    for (int mf = 0; mf < MF; mf++)
      af[mf] = *reinterpret_cast<const half8v*>(&As[(wm + mf * 16 + lr) * LD + kg]);
    #pragma unroll
    for (int nf = 0; nf < 4; nf++){
      half8v bf = *reinterpret_cast<const half8v*>(&Bs[(wn + nf * 16 + lr) * LD + kg]);
      #pragma unroll
      for (int mf = 0; mf < MF; mf++)
        acc[mf][nf] = __builtin_amdgcn_mfma_f32_16x16x32_f16(af[mf], bf, acc[mf][nf], 0, 0, 0);
    }
  }
  // epilogue: D row = 4*(l>>4)+r, col = lr
  #pragma unroll
  for (int mf = 0; mf < MF; mf++){
    #pragma unroll
    for (int r = 0; r < 4; r++){
      int row = m0 + wm + mf * 16 + (l >> 4) * 4 + r;
      if (row < M){
        #pragma unroll
        for (int nf = 0; nf < 4; nf++)
          C16[(size_t)row * BN + wn + nf * 16 + lr] = (_Float16)acc[mf][nf][r];
      }
    }
  }
}

// ---------------- aggregation (fp16 gather): out = relu(di*(sum dinv_s h_s) + di^2 h_i + b) ----------------
// one wave per node; DH=128: lane owns cols {2*lane, 2*lane+1}

__global__ __launch_bounds__(256) void agg128h_kernel(const _Float16* __restrict__ h16, const int* __restrict__ row_off,
                                                      const int* __restrict__ csr_src, const float* __restrict__ dinv,
                                                      const float* __restrict__ bias, _Float16* __restrict__ out16, int n){
  int node = blockIdx.x * 4 + (threadIdx.x >> 6);
  if (node >= n) return;
  int lane = threadIdx.x & 63;
  int e = row_off[node], eend = row_off[node + 1];
  float di = dinv[node];
  float ax = 0.f, ay = 0.f;
  for (; e + 8 <= eend; e += 8){
    int s[8]; float w[8]; half2v v[8];
    #pragma unroll
    for (int i = 0; i < 8; i++) s[i] = csr_src[e + i];
    #pragma unroll
    for (int i = 0; i < 8; i++) w[i] = dinv[s[i]];
    #pragma unroll
    for (int i = 0; i < 8; i++)
      v[i] = *reinterpret_cast<const half2v*>(h16 + (size_t)s[i] * 128 + lane * 2);
    #pragma unroll
    for (int i = 0; i < 8; i++){
      ax = fmaf(w[i], (float)v[i][0], ax);
      ay = fmaf(w[i], (float)v[i][1], ay);
    }
  }
  for (; e < eend; ++e){
    int s = csr_src[e];
    float w = dinv[s];
    half2v v = *reinterpret_cast<const half2v*>(h16 + (size_t)s * 128 + lane * 2);
    ax = fmaf(w, (float)v[0], ax);
    ay = fmaf(w, (float)v[1], ay);
  }
  half2v hv = *reinterpret_cast<const half2v*>(h16 + (size_t)node * 128 + lane * 2);
  float2 bv = *reinterpret_cast<const float2*>(bias + lane * 2);
  float ox = fmaxf(fmaf(di, ax, di * di * (float)hv[0]) + bv.x, 0.f);
  float oy = fmaxf(fmaf(di, ay, di * di * (float)hv[1]) + bv.y, 0.f);
  half2v o; o[0] = (_Float16)ox; o[1] = (_Float16)oy;
  *reinterpret_cast<half2v*>(out16 + (size_t)node * 128 + lane * 2) = o;
}

__global__ __launch_bounds__(256) void agg64h_kernel(const _Float16* __restrict__ h16, const int* __restrict__ row_off,
                                                     const int* __restrict__ csr_src, const float* __restrict__ dinv,
                                                     const float* __restrict__ bias, float* __restrict__ out, int n){
  int node = blockIdx.x * 4 + (threadIdx.x >> 6);
  if (node >= n) return;
  int lane = threadIdx.x & 63;
  int e = row_off[node], eend = row_off[node + 1];
  float di = dinv[node];
  float ax = 0.f;
  for (; e + 8 <= eend; e += 8){
    int s[8]; float w[8]; _Float16 v[8];
    #pragma unroll
    for (int i = 0; i < 8; i++) s[i] = csr_src[e + i];
    #pragma unroll
    for (int i = 0; i < 8; i++) w[i] = dinv[s[i]];
    #pragma unroll
    for (int i = 0; i < 8; i++) v[i] = h16[(size_t)s[i] * 64 + lane];
    #pragma unroll
    for (int i = 0; i < 8; i++) ax = fmaf(w[i], (float)v[i], ax);
  }
  for (; e < eend; ++e){
    int s = csr_src[e];
    ax = fmaf(dinv[s], (float)h16[(size_t)s * 64 + lane], ax);
  }
  float hv = (float)h16[(size_t)node * 64 + lane];
  float o = fmaxf(fmaf(di, ax, di * di * hv) + bias[lane], 0.f);
  out[(size_t)node * 64 + lane] = o;
}

// ---------------- classifier: out[i] = dot(g[i], Wc) + bc ----------------

__global__ __launch_bounds__(256) void cls_kernel(const float* __restrict__ g, const float* __restrict__ Wc,
                                                  const float* __restrict__ bc, float* __restrict__ out, int n){
  int node = blockIdx.x * 4 + (threadIdx.x >> 6);
  if (node >= n) return;
  int lane = threadIdx.x & 63;
  float v = g[(size_t)node * 64 + lane] * Wc[lane];
  #pragma unroll
  for (int off = 32; off > 0; off >>= 1) v += __shfl_down(v, off);
  if (lane == 0) out[node] = v + bc[0];
}

// ---------------- launch ----------------

extern "C" void kernel_launch(void* const* d_in, const int* in_sizes, int n_in,
                              void* d_out, int out_size, void* d_ws, size_t ws_size,
                              hipStream_t stream){
  const float* x  = (const float*)d_in[0];
  const int*   ei = (const int*)d_in[1];
  const float* W1 = (const float*)d_in[2];
  const float* b1 = (const float*)d_in[3];
  const float* W2 = (const float*)d_in[4];
  const float* b2 = (const float*)d_in[5];
  const float* W3 = (const float*)d_in[6];
  const float* b3 = (const float*)d_in[7];
  const float* Wc = (const float*)d_in[8];
  const float* bc = (const float*)d_in[9];
  float* out = (float*)d_out;

  int N = in_sizes[0] / 256;
  int E = in_sizes[1] / 2;
  const int* src = ei;
  const int* dst = ei + E;

  char* ws = (char*)d_ws;
  size_t off = 0;
  auto alloc = [&](size_t bytes) -> char* {
    char* p = ws + off;
    off += (bytes + 511) & ~(size_t)511;
    return p;
  };
  int*      counts  = (int*)     alloc((size_t)N * 4);   // reused as cursor after scan
  float*    dinv    = (float*)   alloc((size_t)N * 4);
  int*      row_off = (int*)     alloc(((size_t)N + 1) * 4);
  int*      bsum    = (int*)     alloc(1024);
  int*      bsum_ex = (int*)     alloc(1024);
  int*      csr_src = (int*)     alloc((size_t)E * 4);
  _Float16* bufH    = (_Float16*)alloc((size_t)N * 128 * 2);  // gemm outputs
  _Float16* bufG    = (_Float16*)alloc((size_t)N * 128 * 2);  // agg outputs (fp16)
  float*    bufF    = (float*)   alloc((size_t)N * 64 * 4);   // layer-3 agg output (fp32)
  _Float16* W1t     = (_Float16*)alloc((size_t)256 * 128 * 2);
  _Float16* W2t     = (_Float16*)alloc((size_t)128 * 128 * 2);
  _Float16* W3t     = (_Float16*)alloc((size_t)128 * 64 * 2);

  int NB = (N + 1023) / 1024;

  // weights -> fp16 transposed
  wcvt_kernel<<<cdiv(256 * 128, 256), 256, 0, stream>>>(W1, W1t, 256, 128);
  wcvt_kernel<<<cdiv(128 * 128, 256), 256, 0, stream>>>(W2, W2t, 128, 128);
  wcvt_kernel<<<cdiv(128 * 64, 256), 256, 0, stream>>>(W3, W3t, 128, 64);

  // CSR build
  hipMemsetAsync(counts, 0, (size_t)N * 4, stream);
  count_kernel<<<cdiv(E, 256), 256, 0, stream>>>(dst, counts, E);
  dinv_kernel<<<cdiv(N, 256), 256, 0, stream>>>(counts, dinv, N);
  partial_kernel<<<NB, 256, 0, stream>>>(counts, bsum, N);
  scan_partials_kernel<<<1, 1, 0, stream>>>(bsum, bsum_ex, row_off, NB, N);
  scan_chunk_kernel<<<NB, 256, 0, stream>>>(counts, bsum_ex, row_off, N);
  hipMemsetAsync(counts, 0, (size_t)N * 4, stream);   // counts -> cursor
  csr_fill_kernel<<<cdiv(E, 256), 256, 0, stream>>>(src, dst, row_off, counts, csr_src, E);

  // layer 1: x[N,256] @ W1 -> bufH (fp16); agg -> bufG (fp16)
  mgemm_kernel<128, true ><<<cdiv(N, 128), 256, 0, stream>>>(x, W1t, bufH, N, 256);
  agg128h_kernel<<<cdiv(N, 4), 256, 0, stream>>>(bufH, row_off, csr_src, dinv, b1, bufG, N);
  // layer 2
  mgemm_kernel<128, false><<<cdiv(N, 128), 256, 0, stream>>>(bufG, W2t, bufH, N, 128);
  agg128h_kernel<<<cdiv(N, 4), 256, 0, stream>>>(bufH, row_off, csr_src, dinv, b2, bufG, N);
  // layer 3 (128 -> 64)
  mgemm_kernel<64, false><<<cdiv(N, 128), 256, 0, stream>>>(bufG, W3t, bufH, N, 128);
  agg64h_kernel<<<cdiv(N, 4), 256, 0, stream>>>(bufH, row_off, csr_src, dinv, b3, bufF, N);
  // classifier
  cls_kernel<<<cdiv(N, 4), 256, 0, stream>>>(bufF, Wc, bc, out, N);
}

// Round 5
// 454.845 us; speedup vs baseline: 1.5218x; 1.0818x over previous
//
#include <hip/hip_runtime.h>
#include <cstdint>
#include <cstddef>

typedef __attribute__((ext_vector_type(4))) float f32x4;
typedef __attribute__((ext_vector_type(8))) _Float16 half8v;
typedef __attribute__((ext_vector_type(2))) _Float16 half2v;

static inline int cdiv(int a, int b){ return (a + b - 1) / b; }

// ---------------- fused: weight-convert (blocks 0..223) || degree count (rest) ----------------

__global__ __launch_bounds__(256) void wcvt_count_kernel(const float* __restrict__ W1, _Float16* __restrict__ W1t,
                                                         const float* __restrict__ W2, _Float16* __restrict__ W2t,
                                                         const float* __restrict__ W3, _Float16* __restrict__ W3t,
                                                         const int* __restrict__ dst, int* __restrict__ counts, int E){
  int b = blockIdx.x;
  if (b < 224){
    int i = b * 256 + threadIdx.x;
    // W1: 256x128 = 32768 (blocks 0..127), W2: 128x128 = 16384 (128..191), W3: 128x64 = 8192 (192..223)
    if (b < 128){
      int k = i / 128, n = i & 127;
      W1t[(size_t)n * 256 + k] = (_Float16)W1[i];
    } else if (b < 192){
      int j = i - 128 * 256;
      int k = j / 128, n = j & 127;
      W2t[(size_t)n * 128 + k] = (_Float16)W2[j];
    } else {
      int j = i - 192 * 256;
      int k = j / 64, n = j & 63;
      W3t[(size_t)n * 128 + k] = (_Float16)W3[j];
    }
    return;
  }
  int cb = b - 224;
  int base = cb * 1024 + threadIdx.x;
  #pragma unroll
  for (int j = 0; j < 4; j++){
    int i = base + j * 256;
    if (i < E) atomicAdd(&counts[dst[i]], 1);   // no return -> fire-and-forget
  }
}

// ---------------- block partial sums (+ fused dinv) ----------------

__global__ __launch_bounds__(256) void partial_dinv_kernel(const int* __restrict__ counts, int* __restrict__ bsum,
                                                           float* __restrict__ dinv, int n){
  __shared__ int sdata[256];
  int b = blockIdx.x, t = threadIdx.x;
  int base = b * 1024 + t * 4;
  int s = 0;
  #pragma unroll
  for (int i = 0; i < 4; i++){
    if (base + i < n){
      int c = counts[base + i];
      s += c;
      dinv[base + i] = rsqrtf((float)c + 1.0f);
    }
  }
  sdata[t] = s; __syncthreads();
  for (int off = 128; off > 0; off >>= 1){
    if (t < off) sdata[t] += sdata[t + off];
    __syncthreads();
  }
  if (t == 0) bsum[b] = sdata[0];
}

__global__ void scan_partials_kernel(const int* __restrict__ bsum, int* __restrict__ bsum_ex,
                                     int* __restrict__ row_off, int nblocks, int n){
  int run = 0;
  for (int i = 0; i < nblocks; i++){ bsum_ex[i] = run; run += bsum[i]; }
  row_off[n] = run;
}

__global__ __launch_bounds__(256) void scan_chunk_kernel(const int* __restrict__ counts, const int* __restrict__ bsum_ex,
                                                         int* __restrict__ row_off, int n){
  __shared__ int sdata[256];
  int b = blockIdx.x, t = threadIdx.x;
  int base = b * 1024 + t * 4;
  int c0 = (base + 0 < n) ? counts[base + 0] : 0;
  int c1 = (base + 1 < n) ? counts[base + 1] : 0;
  int c2 = (base + 2 < n) ? counts[base + 2] : 0;
  int c3 = (base + 3 < n) ? counts[base + 3] : 0;
  int tsum = c0 + c1 + c2 + c3;
  sdata[t] = tsum; __syncthreads();
  for (int off = 1; off < 256; off <<= 1){
    int v = (t >= off) ? sdata[t - off] : 0;
    __syncthreads();
    sdata[t] += v;
    __syncthreads();
  }
  int run = bsum_ex[b] + sdata[t] - tsum;
  if (base + 0 < n){ row_off[base + 0] = run; run += c0; }
  if (base + 1 < n){ row_off[base + 1] = run; run += c1; }
  if (base + 2 < n){ row_off[base + 2] = run; run += c2; }
  if (base + 3 < n){ row_off[base + 3] = run; run += c3; }
}

// ---------------- MFMA GEMM body: C16[M x BN] = fp16(A @ Bt^T), Bt is [BN x K] fp16 ----------------
// BM=128, BK=32, 4 waves. v_mfma_f32_16x16x32_f16:
//   A: lane l row (l&15), k = 8*(l>>4)+{0..7}; B: lane l col (l&15), same k
//   D: lane l reg r -> row = 4*(l>>4)+r, col = (l&15)

template<int BN, bool A32IN>
__device__ __forceinline__ void gemm_body(int m0, const void* __restrict__ Ain, const _Float16* __restrict__ Bt,
                                          _Float16* __restrict__ C16, int M, int K){
  constexpr int BM = 128, LD = 40;   // stride 40 halves: 16B-aligned rows, <=2-way bank aliasing
  constexpr int MF = (BN == 128) ? 4 : 2;
  __shared__ _Float16 As[BM * LD];
  __shared__ _Float16 Bs[BN * LD];
  const float*    A32 = (const float*)Ain;
  const _Float16* A16 = (const _Float16*)Ain;
  int t = threadIdx.x;
  int w = t >> 6, l = t & 63;
  int wm = (BN == 128) ? (w >> 1) * 64 : w * 32;
  int wn = (BN == 128) ? (w & 1) * 64 : 0;
  int lr = l & 15;
  int kg = (l >> 4) * 8;

  f32x4 acc[MF][4];
  #pragma unroll
  for (int i = 0; i < MF; i++)
    #pragma unroll
    for (int j = 0; j < 4; j++){
      f32x4 z = {0.f, 0.f, 0.f, 0.f};
      acc[i][j] = z;
    }

  for (int k0 = 0; k0 < K; k0 += 32){
    __syncthreads();
    #pragma unroll
    for (int j = 0; j < (BM * 4) / 256; j++){
      int i = t + j * 256;
      int row = i >> 2, c = i & 3;
      int gr = m0 + row;
      half8v hv = {(_Float16)0, (_Float16)0, (_Float16)0, (_Float16)0,
                   (_Float16)0, (_Float16)0, (_Float16)0, (_Float16)0};
      if (gr < M){
        if (A32IN){
          const float* ap = A32 + (size_t)gr * K + k0 + c * 8;
          float4 f0 = *reinterpret_cast<const float4*>(ap);
          float4 f1 = *reinterpret_cast<const float4*>(ap + 4);
          hv[0] = (_Float16)f0.x; hv[1] = (_Float16)f0.y; hv[2] = (_Float16)f0.z; hv[3] = (_Float16)f0.w;
          hv[4] = (_Float16)f1.x; hv[5] = (_Float16)f1.y; hv[6] = (_Float16)f1.z; hv[7] = (_Float16)f1.w;
        } else {
          hv = *reinterpret_cast<const half8v*>(A16 + (size_t)gr * K + k0 + c * 8);
        }
      }
      *reinterpret_cast<half8v*>(&As[row * LD + c * 8]) = hv;
    }
    #pragma unroll
    for (int j = 0; j < (BN * 4) / 256; j++){
      int i = t + j * 256;
      int row = i >> 2, c = i & 3;
      *reinterpret_cast<half8v*>(&Bs[row * LD + c * 8]) =
        *reinterpret_cast<const half8v*>(Bt + (size_t)row * K + k0 + c * 8);
    }
    __syncthreads();
    half8v af[MF];
    #pragma unroll
    for (int mf = 0; mf < MF; mf++)
      af[mf] = *reinterpret_cast<const half8v*>(&As[(wm + mf * 16 + lr) * LD + kg]);
    #pragma unroll
    for (int nf = 0; nf < 4; nf++){
      half8v bf = *reinterpret_cast<const half8v*>(&Bs[(wn + nf * 16 + lr) * LD + kg]);
      #pragma unroll
      for (int mf = 0; mf < MF; mf++)
        acc[mf][nf] = __builtin_amdgcn_mfma_f32_16x16x32_f16(af[mf], bf, acc[mf][nf], 0, 0, 0);
    }
  }
  #pragma unroll
  for (int mf = 0; mf < MF; mf++){
    #pragma unroll
    for (int r = 0; r < 4; r++){
      int row = m0 + wm + mf * 16 + (l >> 4) * 4 + r;
      if (row < M){
        #pragma unroll
        for (int nf = 0; nf < 4; nf++)
          C16[(size_t)row * BN + wn + nf * 16 + lr] = (_Float16)acc[mf][nf][r];
      }
    }
  }
}

template<int BN, bool A32IN>
__global__ __launch_bounds__(256) void mgemm_kernel(const void* __restrict__ Ain, const _Float16* __restrict__ Bt,
                                                    _Float16* __restrict__ C16, int M, int K){
  gemm_body<BN, A32IN>(blockIdx.x * 128, Ain, Bt, C16, M, K);
}

// ---------------- XCD-partitioned CSR fill ----------------
// fill block fb: xcd = fb%8 (round-robin dispatch heuristic), handles dst in [xcd*PART, ...).
// All writers of a csr_src line live on one XCD -> L2 write-coalescing kills the 64B/edge flush.

__device__ __forceinline__ void fill_body(int fb, const int* __restrict__ src, const int* __restrict__ dst,
                                          const int* __restrict__ row_off, int* __restrict__ cursor,
                                          int* __restrict__ csr_src, int E, int N, int NC){
  int xcd = fb & 7, chunk = fb >> 3;
  int PART = (N + 7) >> 3;
  int lo = xcd * PART;
  int hi = lo + PART; if (hi > N) hi = N;
  int CH = (E + NC - 1) / NC;
  int e0 = chunk * CH;
  int e1 = e0 + CH; if (e1 > E) e1 = E;
  for (int i = e0 + threadIdx.x; i < e1; i += 256){
    int d = dst[i];
    if (d >= lo && d < hi){
      int p = row_off[d] + atomicAdd(&cursor[d], 1);
      csr_src[p] = src[i];
    }
  }
}

// ---------------- fused: GEMM layer 1 (blocks < Gg) || CSR fill (blocks >= FO) ----------------

__global__ __launch_bounds__(256) void gemm1_fill_kernel(const float* __restrict__ x, const _Float16* __restrict__ W1t,
                                                         _Float16* __restrict__ C16, int M, int K,
                                                         const int* __restrict__ src, const int* __restrict__ dst,
                                                         const int* __restrict__ row_off, int* __restrict__ cursor,
                                                         int* __restrict__ csr_src, int E, int N, int NC,
                                                         int Gg, int FO){
  int b = blockIdx.x;
  if (b < Gg){
    gemm_body<128, true>(b * 128, x, W1t, C16, M, K);
  } else if (b >= FO){
    fill_body(b - FO, src, dst, row_off, cursor, csr_src, E, N, NC);
  }
}

// ---------------- aggregation (fp16 gather): out = relu(di*(sum dinv_s h_s) + di^2 h_i + b) ----------------

__global__ __launch_bounds__(256) void agg128h_kernel(const _Float16* __restrict__ h16, const int* __restrict__ row_off,
                                                      const int* __restrict__ csr_src, const float* __restrict__ dinv,
                                                      const float* __restrict__ bias, _Float16* __restrict__ out16, int n){
  int node = blockIdx.x * 4 + (threadIdx.x >> 6);
  if (node >= n) return;
  int lane = threadIdx.x & 63;
  int e = row_off[node], eend = row_off[node + 1];
  float di = dinv[node];
  float ax = 0.f, ay = 0.f;
  for (; e + 8 <= eend; e += 8){
    int s[8]; float w[8]; half2v v[8];
    #pragma unroll
    for (int i = 0; i < 8; i++) s[i] = csr_src[e + i];
    #pragma unroll
    for (int i = 0; i < 8; i++) w[i] = dinv[s[i]];
    #pragma unroll
    for (int i = 0; i < 8; i++)
      v[i] = *reinterpret_cast<const half2v*>(h16 + (size_t)s[i] * 128 + lane * 2);
    #pragma unroll
    for (int i = 0; i < 8; i++){
      ax = fmaf(w[i], (float)v[i][0], ax);
      ay = fmaf(w[i], (float)v[i][1], ay);
    }
  }
  for (; e < eend; ++e){
    int s = csr_src[e];
    float w = dinv[s];
    half2v v = *reinterpret_cast<const half2v*>(h16 + (size_t)s * 128 + lane * 2);
    ax = fmaf(w, (float)v[0], ax);
    ay = fmaf(w, (float)v[1], ay);
  }
  half2v hv = *reinterpret_cast<const half2v*>(h16 + (size_t)node * 128 + lane * 2);
  float2 bv = *reinterpret_cast<const float2*>(bias + lane * 2);
  float ox = fmaxf(fmaf(di, ax, di * di * (float)hv[0]) + bv.x, 0.f);
  float oy = fmaxf(fmaf(di, ay, di * di * (float)hv[1]) + bv.y, 0.f);
  half2v o; o[0] = (_Float16)ox; o[1] = (_Float16)oy;
  *reinterpret_cast<half2v*>(out16 + (size_t)node * 128 + lane * 2) = o;
}

__global__ __launch_bounds__(256) void agg64h_kernel(const _Float16* __restrict__ h16, const int* __restrict__ row_off,
                                                     const int* __restrict__ csr_src, const float* __restrict__ dinv,
                                                     const float* __restrict__ bias, float* __restrict__ out, int n){
  int node = blockIdx.x * 4 + (threadIdx.x >> 6);
  if (node >= n) return;
  int lane = threadIdx.x & 63;
  int e = row_off[node], eend = row_off[node + 1];
  float di = dinv[node];
  float ax = 0.f;
  for (; e + 8 <= eend; e += 8){
    int s[8]; float w[8]; _Float16 v[8];
    #pragma unroll
    for (int i = 0; i < 8; i++) s[i] = csr_src[e + i];
    #pragma unroll
    for (int i = 0; i < 8; i++) w[i] = dinv[s[i]];
    #pragma unroll
    for (int i = 0; i < 8; i++) v[i] = h16[(size_t)s[i] * 64 + lane];
    #pragma unroll
    for (int i = 0; i < 8; i++) ax = fmaf(w[i], (float)v[i], ax);
  }
  for (; e < eend; ++e){
    int s = csr_src[e];
    ax = fmaf(dinv[s], (float)h16[(size_t)s * 64 + lane], ax);
  }
  float hv = (float)h16[(size_t)node * 64 + lane];
  float o = fmaxf(fmaf(di, ax, di * di * hv) + bias[lane], 0.f);
  out[(size_t)node * 64 + lane] = o;
}

// ---------------- classifier ----------------

__global__ __launch_bounds__(256) void cls_kernel(const float* __restrict__ g, const float* __restrict__ Wc,
                                                  const float* __restrict__ bc, float* __restrict__ out, int n){
  int node = blockIdx.x * 4 + (threadIdx.x >> 6);
  if (node >= n) return;
  int lane = threadIdx.x & 63;
  float v = g[(size_t)node * 64 + lane] * Wc[lane];
  #pragma unroll
  for (int off = 32; off > 0; off >>= 1) v += __shfl_down(v, off);
  if (lane == 0) out[node] = v + bc[0];
}

// ---------------- launch ----------------

extern "C" void kernel_launch(void* const* d_in, const int* in_sizes, int n_in,
                              void* d_out, int out_size, void* d_ws, size_t ws_size,
                              hipStream_t stream){
  const float* x  = (const float*)d_in[0];
  const int*   ei = (const int*)d_in[1];
  const float* W1 = (const float*)d_in[2];
  const float* b1 = (const float*)d_in[3];
  const float* W2 = (const float*)d_in[4];
  const float* b2 = (const float*)d_in[5];
  const float* W3 = (const float*)d_in[6];
  const float* b3 = (const float*)d_in[7];
  const float* Wc = (const float*)d_in[8];
  const float* bc = (const float*)d_in[9];
  float* out = (float*)d_out;

  int N = in_sizes[0] / 256;
  int E = in_sizes[1] / 2;
  const int* src = ei;
  const int* dst = ei + E;

  char* ws = (char*)d_ws;
  size_t off = 0;
  auto alloc = [&](size_t bytes) -> char* {
    char* p = ws + off;
    off += (bytes + 511) & ~(size_t)511;
    return p;
  };
  int*      counts  = (int*)     alloc((size_t)N * 4);   // reused as cursor after scan
  float*    dinv    = (float*)   alloc((size_t)N * 4);
  int*      row_off = (int*)     alloc(((size_t)N + 1) * 4);
  int*      bsum    = (int*)     alloc(1024);
  int*      bsum_ex = (int*)     alloc(1024);
  int*      csr_src = (int*)     alloc((size_t)E * 4);
  _Float16* bufH    = (_Float16*)alloc((size_t)N * 128 * 2);  // gemm outputs
  _Float16* bufG    = (_Float16*)alloc((size_t)N * 128 * 2);  // agg outputs (fp16)
  float*    bufF    = (float*)   alloc((size_t)N * 64 * 4);   // layer-3 agg output (fp32)
  _Float16* W1t     = (_Float16*)alloc((size_t)256 * 128 * 2);
  _Float16* W2t     = (_Float16*)alloc((size_t)128 * 128 * 2);
  _Float16* W3t     = (_Float16*)alloc((size_t)128 * 64 * 2);

  int NB = (N + 1023) / 1024;

  // K1: wcvt (224 blocks) || degree count
  hipMemsetAsync(counts, 0, (size_t)N * 4, stream);
  wcvt_count_kernel<<<224 + cdiv(E, 1024), 256, 0, stream>>>(W1, W1t, W2, W2t, W3, W3t, dst, counts, E);
  // K2: scan chain (+ dinv fused)
  partial_dinv_kernel<<<NB, 256, 0, stream>>>(counts, bsum, dinv, N);
  scan_partials_kernel<<<1, 1, 0, stream>>>(bsum, bsum_ex, row_off, NB, N);
  scan_chunk_kernel<<<NB, 256, 0, stream>>>(counts, bsum_ex, row_off, N);
  hipMemsetAsync(counts, 0, (size_t)N * 4, stream);   // counts -> cursor
  // K3: gemm1 || xcd-partitioned fill
  {
    int Gg = cdiv(N, 128);
    int FO = (Gg + 7) & ~7;           // fill offset, multiple of 8 to keep %8 -> XCD mapping
    int NC = 512;                     // edge chunks; fill blocks = 8*NC
    gemm1_fill_kernel<<<FO + 8 * NC, 256, 0, stream>>>(x, W1t, bufH, N, 256,
                                                       src, dst, row_off, counts, csr_src,
                                                       E, N, NC, Gg, FO);
  }
  // layer 1 agg
  agg128h_kernel<<<cdiv(N, 4), 256, 0, stream>>>(bufH, row_off, csr_src, dinv, b1, bufG, N);
  // layer 2
  mgemm_kernel<128, false><<<cdiv(N, 128), 256, 0, stream>>>(bufG, W2t, bufH, N, 128);
  agg128h_kernel<<<cdiv(N, 4), 256, 0, stream>>>(bufH, row_off, csr_src, dinv, b2, bufG, N);
  // layer 3 (128 -> 64)
  mgemm_kernel<64, false><<<cdiv(N, 128), 256, 0, stream>>>(bufG, W3t, bufH, N, 128);
  agg64h_kernel<<<cdiv(N, 4), 256, 0, stream>>>(bufH, row_off, csr_src, dinv, b3, bufF, N);
  // classifier
  cls_kernel<<<cdiv(N, 4), 256, 0, stream>>>(bufF, Wc, bc, out, N);
}